// Round 2
// baseline (449.486 us; speedup 1.0000x reference)
//
#include <hip/hip_runtime.h>

#define FDIM 60
#define MROW 600
#define CDIM 8
#define ODIM 18
#define CH   120
#define NCHUNK 5
#define BLK  512

__global__ void __launch_bounds__(BLK) netfv_kernel(
    const float* __restrict__ x,      // [B*M, F] fp32
    const float* __restrict__ W,      // [F, C]
    const float* __restrict__ covar,  // [F, C]
    const float* __restrict__ bias,   // [C]
    const float* __restrict__ cw2,    // [1, F, C]
    const float* __restrict__ H,      // [2*C*F, OUT]
    float* __restrict__ out)          // [B, OUT]
{
    // xs rows padded to 68: b128-aligned for f%4==0, 2-way max conflicts
    __shared__ __align__(16) float xs[CH * 68];      // 32640 B  (aliased as red8 later)
    __shared__ __align__(16) float actl[CH * CDIM];  // 3840 B
    __shared__ __align__(16) float Wt[CDIM * 64];    // 2048 B (transposed, pad 64)
    __shared__ float biasl[CDIM];
    __shared__ float redA[64];
    __shared__ float redB[64];
    __shared__ float asuml[CDIM];
    __shared__ float n1rs[CDIM];
    __shared__ float n1c_s[CDIM], n2c_s[CDIM];
    __shared__ float scal[2];
    __shared__ __align__(16) float fvl[2 * FDIM * CDIM]; // 3840 B

    const int tid  = threadIdx.x;
    const int b    = blockIdx.x;
    const int lane = tid & 63;
    const int wv   = tid >> 6;

    // one-time: transpose W into LDS, bias
    if (tid < FDIM * CDIM) {
        int f = tid >> 3, c = tid & 7;
        Wt[c * 64 + f] = W[tid];
    }
    if (tid < CDIM) biasl[tid] = bias[tid];

    // phase AB role: 4 threads per row, 16-f slices (last slice = 12)
    const int r_ab  = tid >> 2;        // 0..127, active rows < CH when tid<480
    const int q_ab  = tid & 3;
    const int f0_ab = q_ab * 16;
    const int nv_ab = (q_ab == 3) ? 3 : 4;

    // phase C role: subset (30 rows) x cluster x f-quad
    const int sss  = tid >> 7;         // 0..3
    const int tt   = tid & 127;
    const int c_c  = tt >> 4;          // 0..7
    const int fq_c = tt & 15;          // 0..15, active < 15
    const bool actC = (fq_c < 15);
    const int f0_c = fq_c * 4;
    const int r0_c = sss * 30;

    float4 a1 = {0.f, 0.f, 0.f, 0.f}, a2 = {0.f, 0.f, 0.f, 0.f};
    float asum0 = 0.f, asum1 = 0.f;

    __syncthreads();

    float bl[8];
    #pragma unroll
    for (int c = 0; c < 8; ++c) bl[c] = biasl[c];

    const size_t rowbase = (size_t)b * (MROW * FDIM);

    for (int ck = 0; ck < NCHUNK; ++ck) {
        // ---------- phase AB: load row slice, stage to LDS, logits+softmax ----------
        if (tid < 480) {
            const float* rp = x + rowbase + (size_t)(ck * CH + r_ab) * FDIM + f0_ab;
            float xv[16];
            #pragma unroll
            for (int v = 0; v < 4; ++v) {
                if (v < nv_ab) {
                    float4 u = ((const float4*)rp)[v];
                    xv[4*v+0] = u.x; xv[4*v+1] = u.y;
                    xv[4*v+2] = u.z; xv[4*v+3] = u.w;
                } else {
                    xv[4*v+0] = xv[4*v+1] = xv[4*v+2] = xv[4*v+3] = 0.f;
                }
            }
            #pragma unroll
            for (int v = 0; v < 4; ++v) {
                if (v < nv_ab)
                    *(float4*)&xs[r_ab * 68 + f0_ab + 4*v] =
                        make_float4(xv[4*v], xv[4*v+1], xv[4*v+2], xv[4*v+3]);
            }
            float lg[8];
            #pragma unroll
            for (int c = 0; c < 8; ++c) lg[c] = 0.f;
            #pragma unroll
            for (int c = 0; c < 8; ++c) {
                #pragma unroll
                for (int v = 0; v < 4; ++v) {
                    if (v < nv_ab) {
                        float4 w4 = *(const float4*)&Wt[c * 64 + f0_ab + 4*v];
                        lg[c] = fmaf(xv[4*v+0], w4.x, lg[c]);
                        lg[c] = fmaf(xv[4*v+1], w4.y, lg[c]);
                        lg[c] = fmaf(xv[4*v+2], w4.z, lg[c]);
                        lg[c] = fmaf(xv[4*v+3], w4.w, lg[c]);
                    }
                }
            }
            #pragma unroll
            for (int c = 0; c < 8; ++c) {
                lg[c] += __shfl_xor(lg[c], 1);
                lg[c] += __shfl_xor(lg[c], 2);
                lg[c] += bl[c];
            }
            float mx = lg[0];
            #pragma unroll
            for (int c = 1; c < 8; ++c) mx = fmaxf(mx, lg[c]);
            float s = 0.f;
            #pragma unroll
            for (int c = 0; c < 8; ++c) { lg[c] = __expf(lg[c] - mx); s += lg[c]; }
            float inv = 1.0f / s;
            float av0 = lg[2*q_ab] * inv, av1 = lg[2*q_ab+1] * inv;
            *(float2*)&actl[r_ab * 8 + 2*q_ab] = make_float2(av0, av1);
            asum0 += av0; asum1 += av1;
        }
        __syncthreads();
        // ---------- phase C: fv1/fv2 accumulation ----------
        if (actC) {
            #pragma unroll 5
            for (int rr = 0; rr < 30; ++rr) {
                int r = r0_c + rr;
                float av = actl[r * 8 + c_c];
                float4 xv4 = *(const float4*)&xs[r * 68 + f0_c];
                float t0 = av * xv4.x, t1 = av * xv4.y, t2 = av * xv4.z, t3 = av * xv4.w;
                a1.x += t0; a1.y += t1; a1.z += t2; a1.w += t3;
                a2.x = fmaf(t0, xv4.x, a2.x); a2.y = fmaf(t1, xv4.y, a2.y);
                a2.z = fmaf(t2, xv4.z, a2.z); a2.w = fmaf(t3, xv4.w, a2.w);
            }
        }
        __syncthreads();
    }

    // ---------- a_sum reduction (clusters 2*q_ab, 2*q_ab+1; zeros for tid>=480) ----------
    {
        float v0 = asum0, v1 = asum1;
        v0 += __shfl_down(v0, 4);  v1 += __shfl_down(v1, 4);
        v0 += __shfl_down(v0, 8);  v1 += __shfl_down(v1, 8);
        v0 += __shfl_down(v0, 16); v1 += __shfl_down(v1, 16);
        v0 += __shfl_down(v0, 32); v1 += __shfl_down(v1, 32);
        if (lane < 4) { redA[wv * 8 + 2*lane] = v0; redA[wv * 8 + 2*lane + 1] = v1; }
    }
    __syncthreads();
    if (tid < 64) {
        float v = redA[tid];
        v += __shfl_down(v, 8); v += __shfl_down(v, 16); v += __shfl_down(v, 32);
        if (tid < 8) asuml[tid] = v;
    }
    __syncthreads();

    // ---------- subset reduce through xs alias ----------
    float* red8 = xs;   // xs dead after last chunk
    *(float4*)&red8[tid * 8 + 0] = a1;
    *(float4*)&red8[tid * 8 + 4] = a2;
    __syncthreads();

    float fv1v = 0.f, fv2v = 0.f;
    const int f_e = tid >> 3, c_e = tid & 7;
    if (tid < 480) {
        int fq = f_e >> 2, j = f_e & 3;
        float fv1r = 0.f, fv2r = 0.f;
        #pragma unroll
        for (int s = 0; s < 4; ++s) {
            int bsx = (s * 128 + c_e * 16 + fq) * 8;
            fv1r += red8[bsx + j];
            fv2r += red8[bsx + 4 + j];
        }
        float asv  = asuml[c_e];
        float cw2v = cw2[f_e * 8 + c_e];
        float cv   = covar[f_e * 8 + c_e];
        float cwv  = cv * cv + 1e-6f;
        float rcw  = 1.0f / cwv;
        fv1v = (fv1r - asv * cw2v) * rcw;
        fv2v = (fmaf(asv * cw2v, cw2v, fv2r) - 2.0f * fv1r * cw2v) * rcw * rcw - asv;
    }

    // ---------- norm reductions: per-c sum(fv1^2), total sum(fv2^2) ----------
    {
        float p1 = fv1v * fv1v, p2 = fv2v * fv2v;
        p1 += __shfl_down(p1, 8);  p2 += __shfl_down(p2, 8);
        p1 += __shfl_down(p1, 16); p2 += __shfl_down(p2, 16);
        p1 += __shfl_down(p1, 32); p2 += __shfl_down(p2, 32);
        if (lane < 8) { redA[wv * 8 + lane] = p1; redB[wv * 8 + lane] = p2; }
    }
    __syncthreads();
    if (tid < 64) {
        float q1 = redA[tid], q2 = redB[tid];
        q1 += __shfl_down(q1, 8);  q2 += __shfl_down(q2, 8);
        q1 += __shfl_down(q1, 16); q2 += __shfl_down(q2, 16);
        q1 += __shfl_down(q1, 32); q2 += __shfl_down(q2, 32);
        if (tid < 8) { n1c_s[tid] = q1; n2c_s[tid] = q2; }
    }
    __syncthreads();
    if (tid == 0) {
        float S1 = 0.f, S2 = 0.f;
        #pragma unroll
        for (int c = 0; c < 8; ++c) {
            float rs = rsqrtf(fmaxf(n1c_s[c], 1e-12f));
            n1rs[c] = rs;
            S1 += n1c_s[c] * rs * rs;
            S2 += n2c_s[c];
        }
        scal[0] = rsqrtf(fmaxf(S1, 1e-12f));
        scal[1] = rsqrtf(fmaxf(S2, 1e-12f));
    }
    __syncthreads();
    if (tid < 480) {
        float fv1f = fv1v * n1rs[c_e] * scal[0];
        float fv2f = fv2v * scal[1];
        fvl[f_e * 8 + c_e]       = fv1f;
        fvl[480 + f_e * 8 + c_e] = fv2f;
    }
    __syncthreads();

    // ---------- GEMV: out[o] = fv . H[:, o] ----------
    for (int o = wv; o < ODIM; o += 8) {
        float sacc = 0.f;
        #pragma unroll 5
        for (int i = lane; i < 960; i += 64)
            sacc = fmaf(fvl[i], H[i * ODIM + o], sacc);
        sacc += __shfl_down(sacc, 32);
        sacc += __shfl_down(sacc, 16);
        sacc += __shfl_down(sacc, 8);
        sacc += __shfl_down(sacc, 4);
        sacc += __shfl_down(sacc, 2);
        sacc += __shfl_down(sacc, 1);
        if (lane == 0) out[(size_t)b * ODIM + o] = sacc;
    }
}

extern "C" void kernel_launch(void* const* d_in, const int* in_sizes, int n_in,
                              void* d_out, int out_size, void* d_ws, size_t ws_size,
                              hipStream_t stream) {
    const float* x     = (const float*)d_in[0];
    const float* W     = (const float*)d_in[1];
    const float* covar = (const float*)d_in[2];
    const float* bias  = (const float*)d_in[3];
    const float* cw2   = (const float*)d_in[4];
    const float* H     = (const float*)d_in[5];
    float* outp = (float*)d_out;

    const int Bn = in_sizes[0] / (MROW * FDIM);   // 2048
    hipLaunchKernelGGL(netfv_kernel, dim3(Bn), dim3(BLK), 0, stream,
                       x, W, covar, bias, cw2, H, outp);
}

// Round 3
// 440.543 us; speedup vs baseline: 1.0203x; 1.0203x over previous
//
#include <hip/hip_runtime.h>

#define FDIM 60
#define MROW 600
#define CDIM 8
#define ODIM 18
#define CH   128
#define NCHUNK 5
#define BLK  512

typedef short bf16x8 __attribute__((ext_vector_type(8)));
typedef float f32x4  __attribute__((ext_vector_type(4)));

// RNE pack two fp32 -> bf16x2 (lo = low half, hi = high half)
__device__ __forceinline__ unsigned int packrne2(float lo, float hi) {
    unsigned int ul = __float_as_uint(lo), uh = __float_as_uint(hi);
    ul = (ul + 0x7fffu + ((ul >> 16) & 1u)) >> 16;
    uh = (uh + 0x7fffu + ((uh >> 16) & 1u)) & 0xffff0000u;
    return (ul & 0xffffu) | uh;
}

__global__ void __launch_bounds__(BLK, 4) netfv_kernel(
    const float* __restrict__ x,      // [B*M, F] fp32
    const float* __restrict__ W,      // [F, C]
    const float* __restrict__ covar,  // [F, C]
    const float* __restrict__ bias,   // [C]
    const float* __restrict__ cw2,    // [1, F, C]
    const float* __restrict__ H,      // [2*C*F, OUT]
    float* __restrict__ out)          // [B, OUT]
{
    // k-major bf16 tiles, row stride 136 (16B-aligned), kblk^(f>>3) swizzle
    __shared__ __align__(16) short xsT1[64 * 136];   // x   [f][m] 17408 B
    __shared__ __align__(16) short xsT2[64 * 136];   // x^2 [f][m] 17408 B
    __shared__ __align__(16) short actT[16 * 136];   // act [c][m] 4352 B (c>=8 zero)
    __shared__ __align__(16) float Wt[8 * 64];       // W^T, f>=60 zero
    __shared__ __align__(16) float fvbuf[1024];      // raw fv1|fv2 [f*8+c]
    __shared__ __align__(16) float fvl[960];
    __shared__ float redA[64], redB[64];
    __shared__ float asuml[8], n1rs[8], n1c_s[8], n2c_s[8], scal[2];

    const int tid  = threadIdx.x;
    const int b    = blockIdx.x;
    const int lane = tid & 63;
    const int wv   = tid >> 6;
    const int mg   = tid >> 3;      // row-pair 0..63
    const int fs   = tid & 7;       // f-slice (8 floats)

    // one-time init: Wt transpose (zero-padded), actT c>=8 zeroed
    { int c = tid >> 6, f = tid & 63; Wt[c * 64 + f] = (f < FDIM) ? W[f * 8 + c] : 0.f; }
    {
        unsigned int* az = (unsigned int*)(actT + 8 * 136);
        for (int i = tid; i < 544; i += BLK) az[i] = 0u;
    }
    float bl[8];
    #pragma unroll
    for (int c = 0; c < 8; ++c) bl[c] = bias[c];

    const int fvsel = wv & 1;       // 0: fv1 (x), 1: fv2 (x^2)
    const int tile  = wv >> 1;      // f-tile 0..3
    const int ln15  = lane & 15;
    const int quad  = lane >> 4;
    f32x4 acc = {0.f, 0.f, 0.f, 0.f};
    float asum_l = 0.f;

    __syncthreads();

    const size_t rowbase = (size_t)b * (MROW * FDIM);

    for (int ck = 0; ck < NCHUNK; ++ck) {
        const int r0  = 2 * mg;
        const int r0g = ck * CH + r0;
        const bool valid = (r0g < MROW);     // r0g even, so row pair all-or-none

        float xv0[8], xv1[8];
        float act0 = 0.f, act1 = 0.f;
        if (valid) {
            const float* p0 = x + rowbase + (size_t)r0g * FDIM + 8 * fs;
            const float* p1 = p0 + FDIM;
            float4 A0 = *(const float4*)p0;
            float4 A1 = *(const float4*)p1;
            float4 B0 = {0.f,0.f,0.f,0.f}, B1 = {0.f,0.f,0.f,0.f};
            if (fs < 7) { B0 = *(const float4*)(p0 + 4); B1 = *(const float4*)(p1 + 4); }
            xv0[0]=A0.x; xv0[1]=A0.y; xv0[2]=A0.z; xv0[3]=A0.w;
            xv0[4]=B0.x; xv0[5]=B0.y; xv0[6]=B0.z; xv0[7]=B0.w;
            xv1[0]=A1.x; xv1[1]=A1.y; xv1[2]=A1.z; xv1[3]=A1.w;
            xv1[4]=B1.x; xv1[5]=B1.y; xv1[6]=B1.z; xv1[7]=B1.w;

            // partial logits over this 8-f slice, all 8 clusters, both rows
            float lg0[8], lg1[8];
            #pragma unroll
            for (int c = 0; c < 8; ++c) {
                float4 w0 = *(const float4*)&Wt[c * 64 + 8 * fs];
                float4 w1 = *(const float4*)&Wt[c * 64 + 8 * fs + 4];
                float s0 = 0.f, s1 = 0.f;
                s0 = fmaf(xv0[0], w0.x, s0); s0 = fmaf(xv0[1], w0.y, s0);
                s0 = fmaf(xv0[2], w0.z, s0); s0 = fmaf(xv0[3], w0.w, s0);
                s0 = fmaf(xv0[4], w1.x, s0); s0 = fmaf(xv0[5], w1.y, s0);
                s0 = fmaf(xv0[6], w1.z, s0); s0 = fmaf(xv0[7], w1.w, s0);
                s1 = fmaf(xv1[0], w0.x, s1); s1 = fmaf(xv1[1], w0.y, s1);
                s1 = fmaf(xv1[2], w0.z, s1); s1 = fmaf(xv1[3], w0.w, s1);
                s1 = fmaf(xv1[4], w1.x, s1); s1 = fmaf(xv1[5], w1.y, s1);
                s1 = fmaf(xv1[6], w1.z, s1); s1 = fmaf(xv1[7], w1.w, s1);
                lg0[c] = s0; lg1[c] = s1;
            }
            // butterfly over the 8-lane f-octet: all lanes get full dots
            #pragma unroll
            for (int c = 0; c < 8; ++c) {
                lg0[c] += __shfl_xor(lg0[c], 1);
                lg0[c] += __shfl_xor(lg0[c], 2);
                lg0[c] += __shfl_xor(lg0[c], 4);
                lg1[c] += __shfl_xor(lg1[c], 1);
                lg1[c] += __shfl_xor(lg1[c], 2);
                lg1[c] += __shfl_xor(lg1[c], 4);
                lg0[c] += bl[c]; lg1[c] += bl[c];
            }
            float mx0 = lg0[0], mx1 = lg1[0];
            #pragma unroll
            for (int c = 1; c < 8; ++c) { mx0 = fmaxf(mx0, lg0[c]); mx1 = fmaxf(mx1, lg1[c]); }
            float s0 = 0.f, s1 = 0.f;
            #pragma unroll
            for (int c = 0; c < 8; ++c) {
                lg0[c] = __expf(lg0[c] - mx0); s0 += lg0[c];
                lg1[c] = __expf(lg1[c] - mx1); s1 += lg1[c];
            }
            float i0 = 1.f / s0, i1 = 1.f / s1;
            #pragma unroll
            for (int c = 0; c < 8; ++c)
                if (c == fs) { act0 = lg0[c] * i0; act1 = lg1[c] * i1; }
            asum_l += act0 + act1;
        }
        // act store (always: invalid rows write 0 -> zero MFMA contribution)
        ((unsigned int*)actT)[fs * 68 + mg] = valid ? packrne2(act0, act1) : 0u;
        // x / x^2 transposed bf16 stores (swizzled block index)
        if (valid) {
            const int wbase = (((mg >> 2) ^ fs) << 2) + (mg & 3);
            #pragma unroll
            for (int i = 0; i < 8; ++i) {
                int f = 8 * fs + i;
                int woff = f * 68 + wbase;
                ((unsigned int*)xsT1)[woff] = packrne2(xv0[i], xv1[i]);
                ((unsigned int*)xsT2)[woff] = packrne2(xv0[i] * xv0[i], xv1[i] * xv1[i]);
            }
        }
        __syncthreads();

        // MFMA sweep: wave (fvsel, tile) accumulates its 16x16 tile over 4 K-steps
        {
            const short* xsel = fvsel ? xsT2 : xsT1;
            const int f   = tile * 16 + ln15;
            const int fsw = f >> 3;
            #pragma unroll
            for (int ks = 0; ks < 4; ++ks) {
                bf16x8 av = *(const bf16x8*)(actT + ln15 * 136 + ks * 32 + quad * 8);
                int kblk = ks * 4 + quad;
                bf16x8 bv = *(const bf16x8*)(xsel + f * 136 + ((kblk ^ fsw) << 3));
                acc = __builtin_amdgcn_mfma_f32_16x16x32_bf16(av, bv, acc, 0, 0, 0);
            }
        }
        __syncthreads();
    }

    // ---------- a_sum reduction (thread partial is cluster c=fs) ----------
    {
        float v = asum_l;
        v += __shfl_down(v, 8); v += __shfl_down(v, 16); v += __shfl_down(v, 32);
        if (lane < 8) redA[wv * 8 + lane] = v;
    }
    __syncthreads();
    if (tid < 64) {
        float v = redA[tid];
        v += __shfl_down(v, 8); v += __shfl_down(v, 16); v += __shfl_down(v, 32);
        if (tid < 8) asuml[tid] = v;
    }
    // ---------- store MFMA tiles: D layout col=lane&15 (f), row=quad*4+reg (c) ----------
    if (quad < 2) {
        #pragma unroll
        for (int r = 0; r < 4; ++r) {
            int c = quad * 4 + r;
            int f = tile * 16 + ln15;
            fvbuf[fvsel * 512 + f * 8 + c] = acc[r];
        }
    }
    __syncthreads();

    // ---------- epilogue math ----------
    float fv1v = 0.f, fv2v = 0.f;
    const int f_e = tid >> 3, c_e = tid & 7;
    if (tid < 480) {
        float fv1r = fvbuf[f_e * 8 + c_e];
        float fv2r = fvbuf[512 + f_e * 8 + c_e];
        float asv  = asuml[c_e];
        float cw2v = cw2[f_e * 8 + c_e];
        float cv   = covar[f_e * 8 + c_e];
        float cwv  = cv * cv + 1e-6f;
        float rcw  = 1.0f / cwv;
        fv1v = (fv1r - asv * cw2v) * rcw;
        fv2v = (fmaf(asv * cw2v, cw2v, fv2r) - 2.0f * fv1r * cw2v) * rcw * rcw - asv;
    }

    // ---------- norm reductions: per-c sum(fv1^2), total sum(fv2^2) ----------
    {
        float p1 = fv1v * fv1v, p2 = fv2v * fv2v;
        p1 += __shfl_down(p1, 8);  p2 += __shfl_down(p2, 8);
        p1 += __shfl_down(p1, 16); p2 += __shfl_down(p2, 16);
        p1 += __shfl_down(p1, 32); p2 += __shfl_down(p2, 32);
        if (lane < 8) { redA[wv * 8 + lane] = p1; redB[wv * 8 + lane] = p2; }
    }
    __syncthreads();
    if (tid < 64) {
        float q1 = redA[tid], q2 = redB[tid];
        q1 += __shfl_down(q1, 8);  q2 += __shfl_down(q2, 8);
        q1 += __shfl_down(q1, 16); q2 += __shfl_down(q2, 16);
        q1 += __shfl_down(q1, 32); q2 += __shfl_down(q2, 32);
        if (tid < 8) { n1c_s[tid] = q1; n2c_s[tid] = q2; }
    }
    __syncthreads();
    if (tid == 0) {
        float S1 = 0.f, S2 = 0.f;
        #pragma unroll
        for (int c = 0; c < 8; ++c) {
            float rs = rsqrtf(fmaxf(n1c_s[c], 1e-12f));
            n1rs[c] = rs;
            S1 += n1c_s[c] * rs * rs;
            S2 += n2c_s[c];
        }
        scal[0] = rsqrtf(fmaxf(S1, 1e-12f));
        scal[1] = rsqrtf(fmaxf(S2, 1e-12f));
    }
    __syncthreads();
    if (tid < 480) {
        fvl[f_e * 8 + c_e]       = fv1v * n1rs[c_e] * scal[0];
        fvl[480 + f_e * 8 + c_e] = fv2v * scal[1];
    }
    __syncthreads();

    // ---------- GEMV: out[o] = fv . H[:, o] ----------
    for (int o = wv; o < ODIM; o += 8) {
        float sacc = 0.f;
        #pragma unroll 5
        for (int i = lane; i < 960; i += 64)
            sacc = fmaf(fvl[i], H[i * ODIM + o], sacc);
        sacc += __shfl_down(sacc, 32);
        sacc += __shfl_down(sacc, 16);
        sacc += __shfl_down(sacc, 8);
        sacc += __shfl_down(sacc, 4);
        sacc += __shfl_down(sacc, 2);
        sacc += __shfl_down(sacc, 1);
        if (lane == 0) out[(size_t)b * ODIM + o] = sacc;
    }
}

extern "C" void kernel_launch(void* const* d_in, const int* in_sizes, int n_in,
                              void* d_out, int out_size, void* d_ws, size_t ws_size,
                              hipStream_t stream) {
    const float* x     = (const float*)d_in[0];
    const float* W     = (const float*)d_in[1];
    const float* covar = (const float*)d_in[2];
    const float* bias  = (const float*)d_in[3];
    const float* cw2   = (const float*)d_in[4];
    const float* H     = (const float*)d_in[5];
    float* outp = (float*)d_out;

    const int Bn = in_sizes[0] / (MROW * FDIM);   // 2048
    hipLaunchKernelGGL(netfv_kernel, dim3(Bn), dim3(BLK), 0, stream,
                       x, W, covar, bias, cw2, H, outp);
}

// Round 4
// 440.262 us; speedup vs baseline: 1.0210x; 1.0006x over previous
//
#include <hip/hip_runtime.h>

#define FDIM 60
#define MROW 600
#define CDIM 8
#define ODIM 18
#define CH   128
#define NCHUNK 5
#define BLK  512

typedef short bf16x8 __attribute__((ext_vector_type(8)));
typedef float f32x4  __attribute__((ext_vector_type(4)));

// RNE pack two fp32 -> bf16x2 (lo = low half, hi = high half)
__device__ __forceinline__ unsigned int pk2(float lo, float hi) {
    unsigned int ul = __float_as_uint(lo), uh = __float_as_uint(hi);
    ul = (ul + 0x7fffu + ((ul >> 16) & 1u)) >> 16;
    uh = (uh + 0x7fffu + ((uh >> 16) & 1u)) & 0xffff0000u;
    return (ul & 0xffffu) | uh;
}
__device__ __forceinline__ short f2bf(float f) {
    unsigned int u = __float_as_uint(f);
    u = (u + 0x7fffu + ((u >> 16) & 1u)) >> 16;
    return (short)u;
}

__global__ void __launch_bounds__(BLK, 4) netfv_kernel(
    const float* __restrict__ x,      // [B*M, F] fp32
    const float* __restrict__ W,      // [F, C]
    const float* __restrict__ covar,  // [F, C]
    const float* __restrict__ bias,   // [C]
    const float* __restrict__ cw2,    // [1, F, C]
    const float* __restrict__ H,      // [2*C*F, OUT]
    float* __restrict__ out)          // [B, OUT]
{
    __shared__ __align__(16) short xsT1[64 * 136];   // x   [f][m] k-major, 17408 B
    __shared__ __align__(16) short xsT2[64 * 136];   // x^2 [f][m] k-major, 17408 B
    __shared__ __align__(16) short xsM [128 * 72];   // x   [m][f] m-major, 18432 B
    __shared__ __align__(16) short actT[16 * 136];   // act [c][m] k-major (c>=8 zero)
    __shared__ __align__(16) short WtB [16 * 72];    // W^T bf16 (c>=8 / f>=60 zero)
    __shared__ __align__(16) float fvbuf[1024];      // raw fv1|fv2 [f*8+c]
    __shared__ __align__(16) float fvl[960];
    __shared__ float redA[64], redB[64];
    __shared__ float asuml[8], n1rs[8], n1c_s[8], n2c_s[8], scal[2];

    const int tid  = threadIdx.x;
    const int b    = blockIdx.x;
    const int lane = tid & 63;
    const int wv   = tid >> 6;
    const int mg   = tid >> 3;      // row-pair 0..63
    const int fs   = tid & 7;       // f-slice (8 floats)
    const int ln15 = lane & 15;
    const int quad = lane >> 4;
    const int fvsel = wv & 1;       // 0: fv1 (x), 1: fv2 (x^2)
    const int tile  = wv >> 1;      // f-tile 0..3

    const size_t rowbase = (size_t)b * (MROW * FDIM);
    const float* prow = x + rowbase + (size_t)(2 * mg) * FDIM + 8 * fs;

    // preload chunk 0 early (overlap with init)
    float4 A0, A1, B0, B1;
    B0 = B1 = make_float4(0.f, 0.f, 0.f, 0.f);
    A0 = *(const float4*)prow;
    A1 = *(const float4*)(prow + FDIM);
    if (fs < 7) { B0 = *(const float4*)(prow + 4); B1 = *(const float4*)(prow + FDIM + 4); }

    // --- one-time init: WtB (bf16 W^T, zero-padded), actT rows 8..15 zero ---
    if (tid < 512) {
        int c = tid >> 5, j = tid & 31;
        float v0 = (2 * j     < FDIM) ? W[(2 * j) * CDIM + c % CDIM]     : 0.f;
        float v1 = (2 * j + 1 < FDIM) ? W[(2 * j + 1) * CDIM + c % CDIM] : 0.f;
        if (c >= CDIM) { v0 = 0.f; v1 = 0.f; }
        ((unsigned int*)WtB)[c * 36 + j] = pk2(v0, v1);
    }
    {
        unsigned int* az = (unsigned int*)(actT + 8 * 136);
        for (int i = tid; i < 544; i += BLK) az[i] = 0u;
    }
    __syncthreads();

    // hoisted W A-fragments (constant across chunks) + bias fragment
    const bf16x8 aw0 = *(const bf16x8*)(WtB + ln15 * 72 + quad * 8);
    const bf16x8 aw1 = *(const bf16x8*)(WtB + ln15 * 72 + 32 + quad * 8);
    const float4 lb  = *(const float4*)(bias + (quad & 1) * 4);

    f32x4 acc = {0.f, 0.f, 0.f, 0.f};
    float asum_acc[4] = {0.f, 0.f, 0.f, 0.f};
    const int mloc = wv * 16 + ln15;      // local m handled in logits phase

    for (int ck = 0; ck < NCHUNK; ++ck) {
        const bool valid = (ck * CH + 2 * mg) < MROW;

        // --- prefetch next chunk into registers ---
        float4 nA0, nA1, nB0, nB1;
        nA0 = nA1 = nB0 = nB1 = make_float4(0.f, 0.f, 0.f, 0.f);
        if (ck + 1 < NCHUNK && ((ck + 1) * CH + 2 * mg) < MROW) {
            const float* pn = prow + (size_t)(ck + 1) * (CH * FDIM);
            nA0 = *(const float4*)pn;
            nA1 = *(const float4*)(pn + FDIM);
            if (fs < 7) { nB0 = *(const float4*)(pn + 4); nB1 = *(const float4*)(pn + FDIM + 4); }
        }

        // --- stage current chunk to LDS (3 layouts) ---
        if (valid) {
            float xv0[8] = {A0.x, A0.y, A0.z, A0.w, B0.x, B0.y, B0.z, B0.w};
            float xv1[8] = {A1.x, A1.y, A1.z, A1.w, B1.x, B1.y, B1.z, B1.w};
            // m-major for logits B-operand: 2 x ds_write_b128
            {
                unsigned int q0 = pk2(xv0[0], xv0[1]), q1 = pk2(xv0[2], xv0[3]);
                unsigned int q2 = pk2(xv0[4], xv0[5]), q3 = pk2(xv0[6], xv0[7]);
                *(uint4*)(xsM + (2 * mg) * 72 + 8 * fs) = make_uint4(q0, q1, q2, q3);
                unsigned int s0 = pk2(xv1[0], xv1[1]), s1 = pk2(xv1[2], xv1[3]);
                unsigned int s2 = pk2(xv1[4], xv1[5]), s3 = pk2(xv1[6], xv1[7]);
                *(uint4*)(xsM + (2 * mg + 1) * 72 + 8 * fs) = make_uint4(s0, s1, s2, s3);
            }
            // f-major (k=m) for einsum B-operands, swizzled
            const int wbase = (((mg >> 2) ^ fs) << 2) + (mg & 3);
            #pragma unroll
            for (int i = 0; i < 8; ++i) {
                int woff = (8 * fs + i) * 68 + wbase;
                ((unsigned int*)xsT1)[woff] = pk2(xv0[i], xv1[i]);
                ((unsigned int*)xsT2)[woff] = pk2(xv0[i] * xv0[i], xv1[i] * xv1[i]);
            }
        }
        __syncthreads();

        // --- logits MFMA + distributed softmax ---
        {
            bf16x8 bv0 = *(const bf16x8*)(xsM + mloc * 72 + quad * 8);
            bf16x8 bv1 = *(const bf16x8*)(xsM + mloc * 72 + 32 + quad * 8);
            f32x4 lz = {0.f, 0.f, 0.f, 0.f};
            lz = __builtin_amdgcn_mfma_f32_16x16x32_bf16(aw0, bv0, lz, 0, 0, 0);
            lz = __builtin_amdgcn_mfma_f32_16x16x32_bf16(aw1, bv1, lz, 0, 0, 0);
            float L0 = lz[0] + lb.x, L1 = lz[1] + lb.y;
            float L2 = lz[2] + lb.z, L3 = lz[3] + lb.w;
            float mx = fmaxf(fmaxf(L0, L1), fmaxf(L2, L3));
            mx = fmaxf(mx, __shfl_xor(mx, 16));
            float e0 = __expf(L0 - mx), e1 = __expf(L1 - mx);
            float e2 = __expf(L2 - mx), e3 = __expf(L3 - mx);
            float s = e0 + e1 + e2 + e3;
            s += __shfl_xor(s, 16);
            float inv = __builtin_amdgcn_rcpf(s);
            const bool vm = (ck * CH + mloc) < MROW;
            if (quad < 2) {
                float a0 = vm ? e0 * inv : 0.f, a1v = vm ? e1 * inv : 0.f;
                float a2v = vm ? e2 * inv : 0.f, a3v = vm ? e3 * inv : 0.f;
                asum_acc[0] += a0;  asum_acc[1] += a1v;
                asum_acc[2] += a2v; asum_acc[3] += a3v;
                actT[(quad * 4 + 0) * 136 + mloc] = f2bf(a0);
                actT[(quad * 4 + 1) * 136 + mloc] = f2bf(a1v);
                actT[(quad * 4 + 2) * 136 + mloc] = f2bf(a2v);
                actT[(quad * 4 + 3) * 136 + mloc] = f2bf(a3v);
            }
        }
        __syncthreads();

        // --- einsum MFMA: wave (fvsel, tile) accumulates over 4 K-steps ---
        {
            const short* xsel = fvsel ? xsT2 : xsT1;
            const int f   = tile * 16 + ln15;
            const int fsw = f >> 3;
            #pragma unroll
            for (int ks = 0; ks < 4; ++ks) {
                bf16x8 av = *(const bf16x8*)(actT + ln15 * 136 + ks * 32 + quad * 8);
                int kblk = ks * 4 + quad;
                bf16x8 bv = *(const bf16x8*)(xsel + f * 136 + ((kblk ^ fsw) << 3));
                acc = __builtin_amdgcn_mfma_f32_16x16x32_bf16(av, bv, acc, 0, 0, 0);
            }
        }
        __syncthreads();
        A0 = nA0; A1 = nA1; B0 = nB0; B1 = nB1;
    }

    // ---------- a_sum: asum_acc holds c=quad*4+r partials (quads 0,1) ----------
    #pragma unroll
    for (int r = 0; r < 4; ++r) {
        float v = asum_acc[r];
        v += __shfl_xor(v, 1); v += __shfl_xor(v, 2);
        v += __shfl_xor(v, 4); v += __shfl_xor(v, 8);
        asum_acc[r] = v;
    }
    if (quad < 2 && ln15 == 0) {
        #pragma unroll
        for (int r = 0; r < 4; ++r) redA[wv * 8 + quad * 4 + r] = asum_acc[r];
    }
    __syncthreads();
    if (tid < 64) {
        float v = redA[tid];
        v += __shfl_down(v, 8); v += __shfl_down(v, 16); v += __shfl_down(v, 32);
        if (tid < 8) asuml[tid] = v;
    }
    // ---------- store MFMA tiles: D layout col=ln15 (f), row=quad*4+reg (c) ----------
    if (quad < 2) {
        #pragma unroll
        for (int r = 0; r < 4; ++r)
            fvbuf[fvsel * 512 + (tile * 16 + ln15) * 8 + quad * 4 + r] = acc[r];
    }
    __syncthreads();

    // ---------- epilogue math ----------
    float fv1v = 0.f, fv2v = 0.f;
    const int f_e = tid >> 3, c_e = tid & 7;
    if (tid < 480) {
        float fv1r = fvbuf[f_e * 8 + c_e];
        float fv2r = fvbuf[512 + f_e * 8 + c_e];
        float asv  = asuml[c_e];
        float cw2v = cw2[f_e * 8 + c_e];
        float cv   = covar[f_e * 8 + c_e];
        float cwv  = cv * cv + 1e-6f;
        float rcw  = 1.0f / cwv;
        fv1v = (fv1r - asv * cw2v) * rcw;
        fv2v = (fmaf(asv * cw2v, cw2v, fv2r) - 2.0f * fv1r * cw2v) * rcw * rcw - asv;
    }

    // ---------- norm reductions: per-c sum(fv1^2), total sum(fv2^2) ----------
    {
        float p1 = fv1v * fv1v, p2 = fv2v * fv2v;
        p1 += __shfl_down(p1, 8);  p2 += __shfl_down(p2, 8);
        p1 += __shfl_down(p1, 16); p2 += __shfl_down(p2, 16);
        p1 += __shfl_down(p1, 32); p2 += __shfl_down(p2, 32);
        if (lane < 8) { redA[wv * 8 + lane] = p1; redB[wv * 8 + lane] = p2; }
    }
    __syncthreads();
    if (tid < 64) {
        float q1 = redA[tid], q2 = redB[tid];
        q1 += __shfl_down(q1, 8);  q2 += __shfl_down(q2, 8);
        q1 += __shfl_down(q1, 16); q2 += __shfl_down(q2, 16);
        q1 += __shfl_down(q1, 32); q2 += __shfl_down(q2, 32);
        if (tid < 8) { n1c_s[tid] = q1; n2c_s[tid] = q2; }
    }
    __syncthreads();
    if (tid == 0) {
        float S1 = 0.f, S2 = 0.f;
        #pragma unroll
        for (int c = 0; c < 8; ++c) {
            float rs = rsqrtf(fmaxf(n1c_s[c], 1e-12f));
            n1rs[c] = rs;
            S1 += n1c_s[c] * rs * rs;
            S2 += n2c_s[c];
        }
        scal[0] = rsqrtf(fmaxf(S1, 1e-12f));
        scal[1] = rsqrtf(fmaxf(S2, 1e-12f));
    }
    __syncthreads();
    if (tid < 480) {
        fvl[f_e * 8 + c_e]       = fv1v * n1rs[c_e] * scal[0];
        fvl[480 + f_e * 8 + c_e] = fv2v * scal[1];
    }
    __syncthreads();

    // ---------- GEMV: out[o] = fv . H[:, o] ----------
    for (int o = wv; o < ODIM; o += 8) {
        float sacc = 0.f;
        #pragma unroll 5
        for (int i = lane; i < 960; i += 64)
            sacc = fmaf(fvl[i], H[i * ODIM + o], sacc);
        sacc += __shfl_down(sacc, 32);
        sacc += __shfl_down(sacc, 16);
        sacc += __shfl_down(sacc, 8);
        sacc += __shfl_down(sacc, 4);
        sacc += __shfl_down(sacc, 2);
        sacc += __shfl_down(sacc, 1);
        if (lane == 0) out[(size_t)b * ODIM + o] = sacc;
    }
}

extern "C" void kernel_launch(void* const* d_in, const int* in_sizes, int n_in,
                              void* d_out, int out_size, void* d_ws, size_t ws_size,
                              hipStream_t stream) {
    const float* x     = (const float*)d_in[0];
    const float* W     = (const float*)d_in[1];
    const float* covar = (const float*)d_in[2];
    const float* bias  = (const float*)d_in[3];
    const float* cw2   = (const float*)d_in[4];
    const float* H     = (const float*)d_in[5];
    float* outp = (float*)d_out;

    const int Bn = in_sizes[0] / (MROW * FDIM);   // 2048
    hipLaunchKernelGGL(netfv_kernel, dim3(Bn), dim3(BLK), 0, stream,
                       x, W, covar, bias, cw2, H, outp);
}